// Round 14
// baseline (745.396 us; speedup 1.0000x reference)
//
#include <hip/hip_runtime.h>

#define N_READ   200000
#define N_INTRON 50000
#define N_EDGES  2000000

#define NB    256                          // edge-segment blocks for hist/scatter
#define EPB   ((N_EDGES + NB - 1) / NB)    // 7813 edges per block
#define NBUK  782                          // buckets per direction (782*64>=50000, 782*256>=200000)
#define SH_I  6                            // intron bucket shift: 64 introns/bucket
#define SH_R  8                            // read bucket shift: 256 reads/bucket
#define NITEMS (NBUK * NB)                 // 200192 (divisible by 256)
#define CSH   11                           // sweep chunk shift: 2048 intron rows = 512KB window
#define NCHP  32                           // chunk slots (25 used)
#define NGRP  (N_READ / 4)                 // 50000 groups of 4 read nodes

typedef float f4 __attribute__((ext_vector_type(4)));
typedef float f2 __attribute__((ext_vector_type(2)));
typedef unsigned u32x4 __attribute__((ext_vector_type(4)));
typedef unsigned short u16x4 __attribute__((ext_vector_type(4)));

// bf16 helpers: storage-only bf16; all math in f32.
static __device__ __forceinline__ unsigned short f2bf(float x) {
  unsigned u = __builtin_bit_cast(unsigned, x);
  u = (u + 0x7fffu + ((u >> 16) & 1u)) >> 16;  // RTNE
  return (unsigned short)u;
}
static __device__ __forceinline__ float blo(unsigned u) {
  return __builtin_bit_cast(float, u << 16);
}
static __device__ __forceinline__ float bhi(unsigned u) {
  return __builtin_bit_cast(float, u & 0xffff0000u);
}

// ---------------- bucket histograms (per-block LDS, no global atomics) ----------------
__global__ void kb_hist(const int* __restrict__ src, const int* __restrict__ dst,
                        int* __restrict__ histI, int* __restrict__ histR) {
  __shared__ int hI[1024], hR[1024];
  const int t = threadIdx.x, b = blockIdx.x;
  for (int k = t; k < 1024; k += 256) { hI[k] = 0; hR[k] = 0; }
  __syncthreads();
  const int s0 = b * EPB;
  const int s1 = (s0 + EPB < N_EDGES) ? s0 + EPB : N_EDGES;
  for (int i = s0 + t; i < s1; i += 256) {
    atomicAdd(&hI[dst[i] >> SH_I], 1);
    atomicAdd(&hR[src[i] >> SH_R], 1);
  }
  __syncthreads();
  for (int k = t; k < NBUK; k += 256) {
    histI[k * NB + b] = hI[k];
    histR[k * NB + b] = hR[k];
  }
}

// ---------------- exclusive scan (3 phases) ----------------
__global__ void k_scan1(const int* __restrict__ cnt, int* __restrict__ rp,
                        int* __restrict__ bsum, int n) {
  __shared__ int lds[256];
  int t = threadIdx.x;
  int i = blockIdx.x * 256 + t;
  int v = (i < n) ? cnt[i] : 0;
  lds[t] = v;
  __syncthreads();
  for (int off = 1; off < 256; off <<= 1) {
    int x = (t >= off) ? lds[t - off] : 0;
    __syncthreads();
    lds[t] += x;
    __syncthreads();
  }
  if (i < n) rp[i + 1] = lds[t];
  if (t == 255) bsum[blockIdx.x] = lds[255];
}

__global__ void k_scan2(int* __restrict__ bsum, int nb) {
  __shared__ int lds[1024];
  int t = threadIdx.x;
  int v = (t < nb) ? bsum[t] : 0;
  lds[t] = v;
  __syncthreads();
  for (int off = 1; off < 1024; off <<= 1) {
    int x = (t >= off) ? lds[t - off] : 0;
    __syncthreads();
    lds[t] += x;
    __syncthreads();
  }
  if (t < nb) bsum[t] = lds[t];
}

__global__ void k_scan3b(int* __restrict__ rp, const int* __restrict__ bsum, int n) {
  int i = blockIdx.x * 256 + threadIdx.x;
  if (i >= n) return;
  int off = (blockIdx.x == 0) ? 0 : bsum[blockIdx.x - 1];
  rp[i + 1] += off;
  if (i == 0) rp[0] = 0;
}

// ---------------- scatter edges into buckets (LDS cursors, packed u32 records) ----------------
__global__ void kb_scatter(const int* __restrict__ src, const int* __restrict__ dst,
                           const int* __restrict__ scanI, const int* __restrict__ scanR,
                           unsigned* __restrict__ bI, unsigned* __restrict__ bR) {
  __shared__ int cI[1024], cR[1024];
  const int t = threadIdx.x, b = blockIdx.x;
  for (int k = t; k < NBUK; k += 256) {
    cI[k] = scanI[k * NB + b];
    cR[k] = scanR[k * NB + b];
  }
  __syncthreads();
  const int s0 = b * EPB;
  const int s1 = (s0 + EPB < N_EDGES) ? s0 + EPB : N_EDGES;
  for (int i = s0 + t; i < s1; i += 256) {
    int s = src[i], d = dst[i];
    int slot = atomicAdd(&cI[d >> SH_I], 1);
    bI[slot] = ((unsigned)s << SH_I) | (unsigned)(d & 63);        // 18+6 = 24 bits
    int slot2 = atomicAdd(&cR[s >> SH_R], 1);
    bR[slot2] = ((unsigned)d << SH_R) | (unsigned)(s & 255);      // 16+8 = 24 bits
  }
}

// ---------------- fine CSR per bucket (intron side) ----------------
template <int NBINS, int SH, typename PT>
__global__ void kb_fine(const unsigned* __restrict__ bk, const int* __restrict__ scan,
                        int* __restrict__ rp, float* __restrict__ rs,
                        PT* __restrict__ csr, int n_nodes) {
  __shared__ int hist[NBINS], cur[NBINS], lds[256];
  const int t = threadIdx.x, k = blockIdx.x;
  for (int j = t; j < NBINS; j += 256) hist[j] = 0;
  __syncthreads();
  const int s0 = scan[k * NB];
  const int e0 = (k + 1 < NBUK) ? scan[(k + 1) * NB] : N_EDGES;
  for (int i = s0 + t; i < e0; i += 256) atomicAdd(&hist[bk[i] & (NBINS - 1)], 1);
  __syncthreads();
  int v = (t < NBINS) ? hist[t] : 0;
  lds[t] = v;
  __syncthreads();
  for (int off = 1; off < 256; off <<= 1) {
    int x = (t >= off) ? lds[t - off] : 0;
    __syncthreads();
    lds[t] += x;
    __syncthreads();
  }
  if (t < NBINS) {
    int base = s0 + lds[t] - hist[t];
    cur[t] = base;
    int n = k * NBINS + t;
    if (n < n_nodes) {
      rp[n] = base;
      rs[n] = rsqrtf((float)(hist[t] > 0 ? hist[t] : 1));
    }
  }
  if (k == NBUK - 1 && t == 0) rp[n_nodes] = N_EDGES;
  __syncthreads();
  for (int i = s0 + t; i < e0; i += 256) {
    unsigned v2 = bk[i];
    int slot = atomicAdd(&cur[v2 & (NBINS - 1)], 1);
    csr[slot] = (PT)(v2 >> SH);
  }
}

// ---------------- fine CSR, read side: per-group-of-4 chunk-major record stream ----------------
// bR records: (intron << 8) | (read & 255). Output records: ((read&3)<<16) | intron,
// grouped by read-group (read>>2), ordered chunk-major (512KB source windows) within group.
__global__ void kb_fine_r(const unsigned* __restrict__ bk, const int* __restrict__ scan,
                          int* __restrict__ rpg, float* __restrict__ rs,
                          unsigned* __restrict__ recs, int n_nodes) {
  __shared__ int cnt2[64 * NCHP], cur2[64 * NCHP], lds[256], cntn[256];
  const int t = threadIdx.x, k = blockIdx.x;
  for (int j = t; j < 64 * NCHP; j += 256) cnt2[j] = 0;
  cntn[t] = 0;
  __syncthreads();
  const int s0 = scan[k * NB];
  const int e0 = (k + 1 < NBUK) ? scan[(k + 1) * NB] : N_EDGES;
  for (int i = s0 + t; i < e0; i += 256) {
    unsigned v = bk[i];
    int rl = v & 255;
    int c = (int)(v >> 8) >> CSH;
    atomicAdd(&cnt2[(rl >> 2) * NCHP + c], 1);
    atomicAdd(&cntn[rl], 1);
  }
  __syncthreads();
  int tg = 0;
  if (t < 64) {
#pragma unroll
    for (int c = 0; c < NCHP; ++c) tg += cnt2[t * NCHP + c];
  }
  lds[t] = tg;
  __syncthreads();
  for (int off = 1; off < 64; off <<= 1) {
    int x = (t >= off) ? lds[t - off] : 0;
    __syncthreads();
    lds[t] += x;
    __syncthreads();
  }
  if (t < 64) {
    int base = s0 + lds[t] - tg;
    int run = base;
#pragma unroll
    for (int c = 0; c < NCHP; ++c) { cur2[t * NCHP + c] = run; run += cnt2[t * NCHP + c]; }
    int g = k * 64 + t;
    if (g < NGRP) rpg[g] = base;
  }
  {
    int n = k * 256 + t;
    if (n < n_nodes) {
      int d = cntn[t];
      rs[n] = rsqrtf((float)(d > 0 ? d : 1));
    }
  }
  if (k == NBUK - 1 && t == 0) rpg[NGRP] = N_EDGES;
  __syncthreads();
  for (int i = s0 + t; i < e0; i += 256) {
    unsigned v = bk[i];
    int rl = v & 255;
    unsigned intron = v >> 8;
    int c = (int)intron >> CSH;
    int slot = atomicAdd(&cur2[(rl >> 2) * NCHP + c], 1);
    recs[slot] = ((unsigned)(rl & 3) << 16) | intron;
  }
}

// ---------------- layer-0 input prep: pad 10->16 and pre-scale by rs_read ----------------
__global__ void k_prep_h0(const float* __restrict__ h_read, const float* __restrict__ rs_r,
                          float* __restrict__ h16) {
  int i = blockIdx.x * blockDim.x + threadIdx.x;
  if (i >= N_READ * 16) return;
  int n = i >> 4, c = i & 15;
  h16[i] = (c < 10) ? h_read[n * 10 + c] * rs_r[n] : 0.0f;
}

__global__ void k_prep_W0(const float* __restrict__ W0, float* __restrict__ W0p) {
  int i = blockIdx.x * blockDim.x + threadIdx.x;
  if (i >= 16 * 64) return;
  int k = i >> 6, j = i & 63;
  W0p[i] = (k < 10) ? W0[k * 64 + j] : 0.0f;
}

// ---------------- dense pre-transform: g = h @ W (bf16 in, f32 math, bf16 out) ----------------
template <int DIN>
__launch_bounds__(256)
__global__ void kx_transform(const unsigned* __restrict__ h32,  // bf16 pairs, row stride DIN/2
                             const float* __restrict__ W,       // [DIN][128]
                             unsigned short* __restrict__ g,    // [n][128] bf16
                             int n_src) {
  constexpr int RS = DIN + 4;
  constexpr int HC = DIN / 2;
  __shared__ float rows[32 * RS];
  const int tid = threadIdx.x;
  const int nbase = blockIdx.x * 32;
  for (int idx = tid; idx < 32 * HC; idx += 256) {
    int r = idx / HC, cp = idx % HC;
    int n = nbase + r;
    unsigned u = (n < n_src) ? h32[(size_t)n * HC + cp] : 0u;
    rows[r * RS + cp * 2] = blo(u);
    rows[r * RS + cp * 2 + 1] = bhi(u);
  }
  __syncthreads();
  const int jg = tid % 32, ng = tid / 32;  // NG=8, NPT=4
  const int j0 = jg * 4;
  f4 acc[4];
#pragma unroll
  for (int p = 0; p < 4; ++p) acc[p] = (f4){0.f, 0.f, 0.f, 0.f};
#pragma unroll 2
  for (int k = 0; k < DIN; k += 4) {
    f4 w[4];
#pragma unroll
    for (int u = 0; u < 4; ++u) w[u] = *(const f4*)&W[(k + u) * 128 + j0];
#pragma unroll
    for (int p = 0; p < 4; ++p) {
      f4 r = *(const f4*)&rows[(ng + p * 8) * RS + k];
#pragma unroll
      for (int u = 0; u < 4; ++u) acc[p] += r[u] * w[u];
    }
  }
#pragma unroll
  for (int p = 0; p < 4; ++p) {
    const int n = nbase + ng + p * 8;
    if (n < n_src) {
      u16x4 o = {f2bf(acc[p][0]), f2bf(acc[p][1]), f2bf(acc[p][2]), f2bf(acc[p][3])};
      *(u16x4*)&g[(size_t)n * 128 + j0] = o;
    }
  }
}

// ---------------- sweep v2: slot-packed chunk-major gather for read-dst layers ----------------
// Wave = 4 slots x 16 lanes, owns one group of 4 read nodes. One dwordx4 gather fetches
// 4 different rows per instr; masked FMA into 4 per-node register accumulators.
// __launch_bounds__(256, 4): 128-VGPR cap so the 8 f4 accumulators + temporaries stay
// in registers (default allocation chose 32 VGPR and spilled to scratch: r13 showed
// WRITE_SIZE 250MB vs 51MB logical, VGPR_Count 32 < ~50 live).
template <bool FC>
__launch_bounds__(256, 4)
__global__ void k_sweep2(const unsigned* __restrict__ g32,  // [50K][64] u32 (2 bf16 each)
                         const int* __restrict__ rpg,       // [NGRP+1] group record starts
                         const unsigned* __restrict__ recs, // ((read&3)<<16)|intron
                         const float* __restrict__ rs_dst,
                         const float* __restrict__ bias,
                         const float* __restrict__ atts, int li,
                         unsigned* __restrict__ hout32,  // [N_READ][64] u32 rows
                         const float* __restrict__ fcw, const float* __restrict__ fcb,
                         float* __restrict__ fcout) {
  const int tid = threadIdx.x;
  const int wave = tid >> 6, lane = tid & 63;
  const int slot = lane >> 4, lc = lane & 15;
  const int group = blockIdx.x * 4 + wave;  // grid 12500 * 4 = 50000 = NGRP
  const int s = rpg[group], e = rpg[group + 1];

  f4 aA[4], aB[4];  // acc[node][cols lc*8..lc*8+7]: aA = first 4, aB = last 4
#pragma unroll
  for (int n = 0; n < 4; ++n) {
    aA[n] = (f4){0.f, 0.f, 0.f, 0.f};
    aB[n] = (f4){0.f, 0.f, 0.f, 0.f};
  }

  for (int base = s; base < e; base += 64) {
    int idx = base + lane;
    if (idx > N_EDGES - 1) idx = N_EDGES - 1;
    unsigned rec = recs[idx];  // one batch load per <=64 records
    int m = e - base;
    if (m > 64) m = 64;
    for (int r = 0; r < m; r += 4) {
      unsigned rc = (unsigned)__shfl((int)rec, r + slot, 64);
      int id = (int)(rc & 0xffffu);
      int nl = (int)((rc >> 16) & 3u);
      float act = ((r + slot) < m) ? 1.f : 0.f;
      u32x4 v = *(const u32x4*)(g32 + (size_t)id * 64 + lc * 4);  // 4 rows / instr
      f4 vA = {blo(v.x), bhi(v.x), blo(v.y), bhi(v.y)};
      f4 vB = {blo(v.z), bhi(v.z), blo(v.w), bhi(v.w)};
      float m0 = (nl == 0) ? act : 0.f;
      float m1 = (nl == 1) ? act : 0.f;
      float m2 = (nl == 2) ? act : 0.f;
      float m3 = (nl == 3) ? act : 0.f;
      aA[0] += vA * m0; aB[0] += vB * m0;
      aA[1] += vA * m1; aB[1] += vB * m1;
      aA[2] += vA * m2; aB[2] += vB * m2;
      aA[3] += vA * m3; aB[3] += vB * m3;
    }
  }

  // cross-slot reduce (each node's sum is spread over the 4 slots' lane sets)
#pragma unroll
  for (int n = 0; n < 4; ++n) {
#pragma unroll
    for (int j = 0; j < 4; ++j) {
      aA[n][j] += __shfl_xor(aA[n][j], 16);
      aA[n][j] += __shfl_xor(aA[n][j], 32);
      aB[n][j] += __shfl_xor(aB[n][j], 16);
      aB[n][j] += __shfl_xor(aB[n][j], 32);
    }
  }

  // slot s finishes node group*4+s
  f4 sA = aA[0], sB = aB[0];
  if (slot == 1) { sA = aA[1]; sB = aB[1]; }
  if (slot == 2) { sA = aA[2]; sB = aB[2]; }
  if (slot == 3) { sA = aA[3]; sB = aB[3]; }
  const int n = group * 4 + slot;
  const float rsd = rs_dst[n];
  const float gate = 1.f / (1.f + __expf(-atts[li]));
  f4 bA = *(const f4*)&bias[lc * 8];
  f4 bB = *(const f4*)&bias[lc * 8 + 4];
  f4 vA = (sA * rsd + bA) * gate;
  f4 vB = (sB * rsd + bB) * gate;
#pragma unroll
  for (int j = 0; j < 4; ++j) {
    vA[j] = fmaxf(vA[j], 0.f);
    vB[j] = fmaxf(vB[j], 0.f);
  }
  if constexpr (!FC) {
    vA *= rsd;  // prescale for next layer (rs_next == rs_dst here)
    vB *= rsd;
    u32x4 o;
    o.x = (unsigned)f2bf(vA[0]) | ((unsigned)f2bf(vA[1]) << 16);
    o.y = (unsigned)f2bf(vA[2]) | ((unsigned)f2bf(vA[3]) << 16);
    o.z = (unsigned)f2bf(vB[0]) | ((unsigned)f2bf(vB[1]) << 16);
    o.w = (unsigned)f2bf(vB[2]) | ((unsigned)f2bf(vB[3]) << 16);
    *(u32x4*)(hout32 + (size_t)n * 64 + lc * 4) = o;
  } else {
    // fc: lane lc holds cols lc*8..lc*8+7; fcw flat[k*2+c] = flat[lc*16 + 2j + c]
    f4 w0 = *(const f4*)&fcw[lc * 16];
    f4 w1 = *(const f4*)&fcw[lc * 16 + 4];
    f4 w2 = *(const f4*)&fcw[lc * 16 + 8];
    f4 w3 = *(const f4*)&fcw[lc * 16 + 12];
    float s0 = vA[0] * w0[0] + vA[1] * w0[2] + vA[2] * w1[0] + vA[3] * w1[2]
             + vB[0] * w2[0] + vB[1] * w2[2] + vB[2] * w3[0] + vB[3] * w3[2];
    float s1 = vA[0] * w0[1] + vA[1] * w0[3] + vA[2] * w1[1] + vA[3] * w1[3]
             + vB[0] * w2[1] + vB[1] * w2[3] + vB[2] * w3[1] + vB[3] * w3[3];
    s0 += __shfl_xor(s0, 1); s0 += __shfl_xor(s0, 2);
    s0 += __shfl_xor(s0, 4); s0 += __shfl_xor(s0, 8);
    s1 += __shfl_xor(s1, 1); s1 += __shfl_xor(s1, 2);
    s1 += __shfl_xor(s1, 4); s1 += __shfl_xor(s1, 8);
    if (lc == 0) {
      fcout[n * 2] = s0 + fcb[0];
      fcout[n * 2 + 1] = s1 + fcb[1];
    }
  }
}

// ---------------- fused aggregate + GEMM + epilogue layer (intron-dst: L0, L2, L4) ----------------
template <int DIN, int DOUT, bool BF16SRC, typename ET>
__launch_bounds__(256)
__global__ void k_layer(const void* __restrict__ hsrc_, const int* __restrict__ rp,
                        const ET* __restrict__ eidx, const float* __restrict__ rs_dst,
                        const float* __restrict__ W, const float* __restrict__ bias,
                        const float* __restrict__ atts, int li,
                        const float* __restrict__ rs_next,
                        void* __restrict__ hout_, int n_dst) {
  constexpr int NT = 32;
  constexpr int RSTR = DIN + 4;
  __shared__ float rows[NT * RSTR];
  __shared__ int rpl[NT + 1];
  const int tid = threadIdx.x;
  const int nbase = blockIdx.x * NT;
  const int team = tid >> 6, lane = tid & 63;
  const float* hs_f = (const float*)hsrc_;
  const unsigned short* hs_b = (const unsigned short*)hsrc_;

  constexpr int LPS = (DIN * (BF16SRC ? 2 : 4)) / 16;  // lanes per source row
  constexpr int SLOTS = 64 / LPS;
  const int slot = lane / LPS, lc = lane % LPS;

  if (tid <= NT) {
    int nn = nbase + tid;
    if (nn > n_dst) nn = n_dst;
    rpl[tid] = rp[nn];
  }
  __syncthreads();

  {
    int p0 = rpl[team * 8] + lane;
    if (p0 > N_EDGES - 1) p0 = N_EDGES - 1;
    int idsC = (int)eidx[p0];

    for (int t8 = 0; t8 < 8; ++t8) {
      const int t = team * 8 + t8;
      const int e0 = rpl[t], e1 = rpl[t + 1];
      const int deg = e1 - e0;
      int pn = e1 + lane;
      if (pn > N_EDGES - 1) pn = N_EDGES - 1;
      int idsN = (int)eidx[pn];

      f4 accA = {0.f, 0.f, 0.f, 0.f};
      f4 accB = {0.f, 0.f, 0.f, 0.f};
      int processed = 0;
      while (processed < deg) {
        int m = deg - processed;
        if (m > 64) m = 64;
        if (processed > 0) {
          int pr = e0 + processed + lane;
          if (pr > N_EDGES - 1) pr = N_EDGES - 1;
          idsC = (int)eidx[pr];
        }
        for (int r = 0; r < m; r += SLOTS) {
          int idv = __shfl(idsC, r + slot, 64);
          if constexpr (BF16SRC) {
            u32x4 v = *(const u32x4*)(hs_b + (size_t)idv * DIN + lc * 8);
            if (r + slot < m) {
              accA[0] += blo(v.x); accA[1] += bhi(v.x);
              accA[2] += blo(v.y); accA[3] += bhi(v.y);
              accB[0] += blo(v.z); accB[1] += bhi(v.z);
              accB[2] += blo(v.w); accB[3] += bhi(v.w);
            }
          } else {
            f4 v = *(const f4*)(hs_f + (size_t)idv * DIN + lc * 4);
            if (r + slot < m) accA += v;
          }
        }
        processed += m;
      }
      idsC = idsN;

#pragma unroll
      for (int off = LPS; off < 64; off <<= 1) {
#pragma unroll
        for (int k = 0; k < 4; ++k) accA[k] += __shfl_xor(accA[k], off);
        if constexpr (BF16SRC) {
#pragma unroll
          for (int k = 0; k < 4; ++k) accB[k] += __shfl_xor(accB[k], off);
        }
      }
      if (slot == 0) {
        const int n = nbase + t;
        const float rsd = (n < n_dst) ? rs_dst[n] : 0.f;
        if constexpr (BF16SRC) {
          *(f4*)&rows[t * RSTR + lc * 8] = accA * rsd;
          *(f4*)&rows[t * RSTR + lc * 8 + 4] = accB * rsd;
        } else {
          *(f4*)&rows[t * RSTR + lc * 4] = accA * rsd;
        }
      }
    }
  }
  __syncthreads();

  constexpr int JG = DOUT / 4;
  constexpr int NG = 256 / JG;
  constexpr int NPT = NT / NG;
  const int jg = tid % JG, ng = tid / JG;
  const int j0 = jg * 4;

  f4 acc[NPT];
#pragma unroll
  for (int p = 0; p < NPT; ++p) acc[p] = (f4){0.f, 0.f, 0.f, 0.f};

#pragma unroll 2
  for (int k = 0; k < DIN; k += 4) {
    f4 w[4];
#pragma unroll
    for (int u = 0; u < 4; ++u) w[u] = *(const f4*)&W[(k + u) * DOUT + j0];
#pragma unroll
    for (int p = 0; p < NPT; ++p) {
      f4 r = *(const f4*)&rows[(ng + p * NG) * RSTR + k];
#pragma unroll
      for (int u = 0; u < 4; ++u) acc[p] += r[u] * w[u];
    }
  }

  const float gate = 1.f / (1.f + __expf(-atts[li]));
  const f4 b4 = *(const f4*)&bias[j0];
#pragma unroll
  for (int p = 0; p < NPT; ++p) {
    const int nl = ng + p * NG;
    const int n = nbase + nl;
    if (n < n_dst) {
      f4 v = (acc[p] + b4) * gate;
#pragma unroll
      for (int c = 0; c < 4; ++c) v[c] = fmaxf(v[c], 0.f);
      if (rs_next) v *= rs_next[n];
      u16x4 o = {f2bf(v[0]), f2bf(v[1]), f2bf(v[2]), f2bf(v[3])};
      *(u16x4*)&((unsigned short*)hout_)[(size_t)n * DOUT + j0] = o;
    }
  }
}

extern "C" void kernel_launch(void* const* d_in, const int* in_sizes, int n_in,
                              void* d_out, int out_size, void* d_ws, size_t ws_size,
                              hipStream_t stream) {
  const float* h_read = (const float*)d_in[0];
  const int* esrc = (const int*)d_in[1];
  const int* edst = (const int*)d_in[2];
  const float* W0 = (const float*)d_in[3];
  const float* b0 = (const float*)d_in[4];
  const float* W1 = (const float*)d_in[5];
  const float* b1 = (const float*)d_in[6];
  const float* W2 = (const float*)d_in[7];
  const float* b2 = (const float*)d_in[8];
  const float* W3 = (const float*)d_in[9];
  const float* b3 = (const float*)d_in[10];
  const float* W4 = (const float*)d_in[11];
  const float* b4 = (const float*)d_in[12];
  const float* W5 = (const float*)d_in[13];
  const float* b5 = (const float*)d_in[14];
  const float* atts = (const float*)d_in[15];
  const float* fcw = (const float*)d_in[16];
  const float* fcb = (const float*)d_in[17];
  float* out = (float*)d_out;

  char* w = (char*)d_ws;
  size_t off = 0;
  auto alloc = [&](size_t bytes) -> void* {
    void* p = w + off;
    off += (bytes + 15) & ~(size_t)15;
    return p;
  };
  int* rp_i = (int*)alloc((N_INTRON + 1) * 4);
  int* rpg = (int*)alloc((NGRP + 1) * 4);  // per-group record starts
  int* bsum = (int*)alloc(1024 * 4);
  float* rs_r = (float*)alloc(N_READ * 4);
  float* rs_i = (float*)alloc(N_INTRON * 4);
  unsigned* recs = (unsigned*)alloc((size_t)N_EDGES * 4);  // sweep records
  int* csr_si_i = (int*)alloc(N_EDGES * 4);                // read ids by intron
  float* W0p = (float*)alloc(16 * 64 * 4);
  int* histI = (int*)alloc(NITEMS * 4);
  int* scanI = (int*)alloc((NITEMS + 1) * 4);
  int* histR = (int*)alloc(NITEMS * 4);
  int* scanR = (int*)alloc((NITEMS + 1) * 4);
  unsigned short* hR = (unsigned short*)alloc((size_t)N_READ * 128 * 2);    // bf16 features
  unsigned short* hI = (unsigned short*)alloc((size_t)N_INTRON * 128 * 2);  // bf16 features
  unsigned short* g = (unsigned short*)alloc((size_t)N_INTRON * 128 * 2);   // pre-transformed
  // Time-multiplexed aliases inside hR's 51.2 MB (dead until the L1 sweep writes it):
  //   h16 (f32, 12.8 MB) lives prep_h0 -> L0 at hR+0;
  //   bucketed edge records live kb_scatter -> kb_fine at hR+16MB (2x8 MB).
  float* h16 = (float*)hR;
  unsigned* bI = (unsigned*)((char*)hR + (size_t)16 * 1024 * 1024);
  unsigned* bR = bI + N_EDGES;

  // --- CSR build ---
  kb_hist<<<NB, 256, 0, stream>>>(esrc, edst, histI, histR);
  k_scan1<<<NITEMS / 256, 256, 0, stream>>>(histI, scanI, bsum, NITEMS);
  k_scan2<<<1, 1024, 0, stream>>>(bsum, NITEMS / 256);
  k_scan3b<<<NITEMS / 256, 256, 0, stream>>>(scanI, bsum, NITEMS);
  k_scan1<<<NITEMS / 256, 256, 0, stream>>>(histR, scanR, bsum, NITEMS);
  k_scan2<<<1, 1024, 0, stream>>>(bsum, NITEMS / 256);
  k_scan3b<<<NITEMS / 256, 256, 0, stream>>>(scanR, bsum, NITEMS);
  kb_scatter<<<NB, 256, 0, stream>>>(esrc, edst, scanI, scanR, bI, bR);
  kb_fine<64, SH_I, int><<<NBUK, 256, 0, stream>>>(bI, scanI, rp_i, rs_i, csr_si_i, N_INTRON);
  kb_fine_r<<<NBUK, 256, 0, stream>>>(bR, scanR, rpg, rs_r, recs, N_READ);

  k_prep_h0<<<(N_READ * 16 + 255) / 256, 256, 0, stream>>>(h_read, rs_r, h16);
  k_prep_W0<<<4, 256, 0, stream>>>(W0, W0p);

  const int gI = (N_INTRON + 31) / 32;  // 1563
  const int gT = (N_INTRON + 31) / 32;  // transform grid
  const int gS = NGRP / 4;              // 12500 sweep blocks (4 groups each)

  // L0: read->intron, 16(pad)->64, f32 src, write hI bf16 (prescaled rs_i)
  k_layer<16, 64, false, int><<<gI, 256, 0, stream>>>(
      h16, rp_i, csr_si_i, rs_i, W0p, b0, atts, 0, rs_i, hI, N_INTRON);
  // L1: transform hI(64) @ W1 -> g(128), then slot-packed sweep -> hR (prescaled rs_r)
  kx_transform<64><<<gT, 256, 0, stream>>>((const unsigned*)hI, W1, g, N_INTRON);
  k_sweep2<false><<<gS, 256, 0, stream>>>((const unsigned*)g, rpg, recs, rs_r, b1, atts, 1,
                                          (unsigned*)hR, nullptr, nullptr, nullptr);
  // L2: read->intron, 128->128, bf16 src hR, write hI (prescaled rs_i)
  k_layer<128, 128, true, int><<<gI, 256, 0, stream>>>(
      hR, rp_i, csr_si_i, rs_i, W2, b2, atts, 2, rs_i, hI, N_INTRON);
  // L3: transform hI @ W3 -> g, sweep -> hR
  kx_transform<128><<<gT, 256, 0, stream>>>((const unsigned*)hI, W3, g, N_INTRON);
  k_sweep2<false><<<gS, 256, 0, stream>>>((const unsigned*)g, rpg, recs, rs_r, b3, atts, 3,
                                          (unsigned*)hR, nullptr, nullptr, nullptr);
  // L4: read->intron, bf16 src hR, write hI
  k_layer<128, 128, true, int><<<gI, 256, 0, stream>>>(
      hR, rp_i, csr_si_i, rs_i, W4, b4, atts, 4, rs_i, hI, N_INTRON);
  // L5: transform hI @ W5 -> g, sweep with fused fc -> out
  kx_transform<128><<<gT, 256, 0, stream>>>((const unsigned*)hI, W5, g, N_INTRON);
  k_sweep2<true><<<gS, 256, 0, stream>>>((const unsigned*)g, rpg, recs, rs_r, b5, atts, 5,
                                         nullptr, fcw, fcb, out);
}

// Round 15
// 634.680 us; speedup vs baseline: 1.1744x; 1.1744x over previous
//
#include <hip/hip_runtime.h>

#define N_READ   200000
#define N_INTRON 50000
#define N_EDGES  2000000

#define NB    256                          // edge-segment blocks for hist/scatter
#define EPB   ((N_EDGES + NB - 1) / NB)    // 7813 edges per block
#define NBUK  782                          // buckets per direction (782*64>=50000, 782*256>=200000)
#define SH_I  6                            // intron bucket shift: 64 introns/bucket
#define SH_R  8                            // read bucket shift: 256 reads/bucket
#define NITEMS (NBUK * NB)                 // 200192 (divisible by 256)
#define CSH   11                           // sweep chunk shift: 2048 intron rows = 512KB window
#define NCHP  32                           // chunk slots (25 used)
#define NGRP  (N_READ / 4)                 // 50000 groups of 4 read nodes

typedef float f4 __attribute__((ext_vector_type(4)));
typedef float f2 __attribute__((ext_vector_type(2)));
typedef unsigned u32x4 __attribute__((ext_vector_type(4)));
typedef unsigned short u16x4 __attribute__((ext_vector_type(4)));

// bf16 helpers: storage-only bf16; all math in f32.
static __device__ __forceinline__ unsigned short f2bf(float x) {
  unsigned u = __builtin_bit_cast(unsigned, x);
  u = (u + 0x7fffu + ((u >> 16) & 1u)) >> 16;  // RTNE
  return (unsigned short)u;
}
static __device__ __forceinline__ float blo(unsigned u) {
  return __builtin_bit_cast(float, u << 16);
}
static __device__ __forceinline__ float bhi(unsigned u) {
  return __builtin_bit_cast(float, u & 0xffff0000u);
}
// cross-slot butterfly reduce (16-lane slots within wave64)
static __device__ __forceinline__ void xred(f4& a) {
#pragma unroll
  for (int j = 0; j < 4; ++j) {
    a[j] += __shfl_xor(a[j], 16);
    a[j] += __shfl_xor(a[j], 32);
  }
}

// ---------------- bucket histograms (per-block LDS, no global atomics) ----------------
__global__ void kb_hist(const int* __restrict__ src, const int* __restrict__ dst,
                        int* __restrict__ histI, int* __restrict__ histR) {
  __shared__ int hI[1024], hR[1024];
  const int t = threadIdx.x, b = blockIdx.x;
  for (int k = t; k < 1024; k += 256) { hI[k] = 0; hR[k] = 0; }
  __syncthreads();
  const int s0 = b * EPB;
  const int s1 = (s0 + EPB < N_EDGES) ? s0 + EPB : N_EDGES;
  for (int i = s0 + t; i < s1; i += 256) {
    atomicAdd(&hI[dst[i] >> SH_I], 1);
    atomicAdd(&hR[src[i] >> SH_R], 1);
  }
  __syncthreads();
  for (int k = t; k < NBUK; k += 256) {
    histI[k * NB + b] = hI[k];
    histR[k * NB + b] = hR[k];
  }
}

// ---------------- exclusive scan (3 phases) ----------------
__global__ void k_scan1(const int* __restrict__ cnt, int* __restrict__ rp,
                        int* __restrict__ bsum, int n) {
  __shared__ int lds[256];
  int t = threadIdx.x;
  int i = blockIdx.x * 256 + t;
  int v = (i < n) ? cnt[i] : 0;
  lds[t] = v;
  __syncthreads();
  for (int off = 1; off < 256; off <<= 1) {
    int x = (t >= off) ? lds[t - off] : 0;
    __syncthreads();
    lds[t] += x;
    __syncthreads();
  }
  if (i < n) rp[i + 1] = lds[t];
  if (t == 255) bsum[blockIdx.x] = lds[255];
}

__global__ void k_scan2(int* __restrict__ bsum, int nb) {
  __shared__ int lds[1024];
  int t = threadIdx.x;
  int v = (t < nb) ? bsum[t] : 0;
  lds[t] = v;
  __syncthreads();
  for (int off = 1; off < 1024; off <<= 1) {
    int x = (t >= off) ? lds[t - off] : 0;
    __syncthreads();
    lds[t] += x;
    __syncthreads();
  }
  if (t < nb) bsum[t] = lds[t];
}

__global__ void k_scan3b(int* __restrict__ rp, const int* __restrict__ bsum, int n) {
  int i = blockIdx.x * 256 + threadIdx.x;
  if (i >= n) return;
  int off = (blockIdx.x == 0) ? 0 : bsum[blockIdx.x - 1];
  rp[i + 1] += off;
  if (i == 0) rp[0] = 0;
}

// ---------------- scatter edges into buckets (LDS cursors, packed u32 records) ----------------
__global__ void kb_scatter(const int* __restrict__ src, const int* __restrict__ dst,
                           const int* __restrict__ scanI, const int* __restrict__ scanR,
                           unsigned* __restrict__ bI, unsigned* __restrict__ bR) {
  __shared__ int cI[1024], cR[1024];
  const int t = threadIdx.x, b = blockIdx.x;
  for (int k = t; k < NBUK; k += 256) {
    cI[k] = scanI[k * NB + b];
    cR[k] = scanR[k * NB + b];
  }
  __syncthreads();
  const int s0 = b * EPB;
  const int s1 = (s0 + EPB < N_EDGES) ? s0 + EPB : N_EDGES;
  for (int i = s0 + t; i < s1; i += 256) {
    int s = src[i], d = dst[i];
    int slot = atomicAdd(&cI[d >> SH_I], 1);
    bI[slot] = ((unsigned)s << SH_I) | (unsigned)(d & 63);        // 18+6 = 24 bits
    int slot2 = atomicAdd(&cR[s >> SH_R], 1);
    bR[slot2] = ((unsigned)d << SH_R) | (unsigned)(s & 255);      // 16+8 = 24 bits
  }
}

// ---------------- fine CSR per bucket (intron side) ----------------
template <int NBINS, int SH, typename PT>
__global__ void kb_fine(const unsigned* __restrict__ bk, const int* __restrict__ scan,
                        int* __restrict__ rp, float* __restrict__ rs,
                        PT* __restrict__ csr, int n_nodes) {
  __shared__ int hist[NBINS], cur[NBINS], lds[256];
  const int t = threadIdx.x, k = blockIdx.x;
  for (int j = t; j < NBINS; j += 256) hist[j] = 0;
  __syncthreads();
  const int s0 = scan[k * NB];
  const int e0 = (k + 1 < NBUK) ? scan[(k + 1) * NB] : N_EDGES;
  for (int i = s0 + t; i < e0; i += 256) atomicAdd(&hist[bk[i] & (NBINS - 1)], 1);
  __syncthreads();
  int v = (t < NBINS) ? hist[t] : 0;
  lds[t] = v;
  __syncthreads();
  for (int off = 1; off < 256; off <<= 1) {
    int x = (t >= off) ? lds[t - off] : 0;
    __syncthreads();
    lds[t] += x;
    __syncthreads();
  }
  if (t < NBINS) {
    int base = s0 + lds[t] - hist[t];
    cur[t] = base;
    int n = k * NBINS + t;
    if (n < n_nodes) {
      rp[n] = base;
      rs[n] = rsqrtf((float)(hist[t] > 0 ? hist[t] : 1));
    }
  }
  if (k == NBUK - 1 && t == 0) rp[n_nodes] = N_EDGES;
  __syncthreads();
  for (int i = s0 + t; i < e0; i += 256) {
    unsigned v2 = bk[i];
    int slot = atomicAdd(&cur[v2 & (NBINS - 1)], 1);
    csr[slot] = (PT)(v2 >> SH);
  }
}

// ---------------- fine CSR, read side: per-group-of-4 chunk-major record stream ----------------
// bR records: (intron << 8) | (read & 255). Output records: ((read&3)<<16) | intron,
// grouped by read-group (read>>2), ordered chunk-major (512KB source windows) within group.
__global__ void kb_fine_r(const unsigned* __restrict__ bk, const int* __restrict__ scan,
                          int* __restrict__ rpg, float* __restrict__ rs,
                          unsigned* __restrict__ recs, int n_nodes) {
  __shared__ int cnt2[64 * NCHP], cur2[64 * NCHP], lds[256], cntn[256];
  const int t = threadIdx.x, k = blockIdx.x;
  for (int j = t; j < 64 * NCHP; j += 256) cnt2[j] = 0;
  cntn[t] = 0;
  __syncthreads();
  const int s0 = scan[k * NB];
  const int e0 = (k + 1 < NBUK) ? scan[(k + 1) * NB] : N_EDGES;
  for (int i = s0 + t; i < e0; i += 256) {
    unsigned v = bk[i];
    int rl = v & 255;
    int c = (int)(v >> 8) >> CSH;
    atomicAdd(&cnt2[(rl >> 2) * NCHP + c], 1);
    atomicAdd(&cntn[rl], 1);
  }
  __syncthreads();
  int tg = 0;
  if (t < 64) {
#pragma unroll
    for (int c = 0; c < NCHP; ++c) tg += cnt2[t * NCHP + c];
  }
  lds[t] = tg;
  __syncthreads();
  for (int off = 1; off < 64; off <<= 1) {
    int x = (t >= off) ? lds[t - off] : 0;
    __syncthreads();
    lds[t] += x;
    __syncthreads();
  }
  if (t < 64) {
    int base = s0 + lds[t] - tg;
    int run = base;
#pragma unroll
    for (int c = 0; c < NCHP; ++c) { cur2[t * NCHP + c] = run; run += cnt2[t * NCHP + c]; }
    int g = k * 64 + t;
    if (g < NGRP) rpg[g] = base;
  }
  {
    int n = k * 256 + t;
    if (n < n_nodes) {
      int d = cntn[t];
      rs[n] = rsqrtf((float)(d > 0 ? d : 1));
    }
  }
  if (k == NBUK - 1 && t == 0) rpg[NGRP] = N_EDGES;
  __syncthreads();
  for (int i = s0 + t; i < e0; i += 256) {
    unsigned v = bk[i];
    int rl = v & 255;
    unsigned intron = v >> 8;
    int c = (int)intron >> CSH;
    int slot = atomicAdd(&cur2[(rl >> 2) * NCHP + c], 1);
    recs[slot] = ((unsigned)(rl & 3) << 16) | intron;
  }
}

// ---------------- layer-0 input prep: pad 10->16 and pre-scale by rs_read ----------------
__global__ void k_prep_h0(const float* __restrict__ h_read, const float* __restrict__ rs_r,
                          float* __restrict__ h16) {
  int i = blockIdx.x * blockDim.x + threadIdx.x;
  if (i >= N_READ * 16) return;
  int n = i >> 4, c = i & 15;
  h16[i] = (c < 10) ? h_read[n * 10 + c] * rs_r[n] : 0.0f;
}

__global__ void k_prep_W0(const float* __restrict__ W0, float* __restrict__ W0p) {
  int i = blockIdx.x * blockDim.x + threadIdx.x;
  if (i >= 16 * 64) return;
  int k = i >> 6, j = i & 63;
  W0p[i] = (k < 10) ? W0[k * 64 + j] : 0.0f;
}

// ---------------- dense pre-transform: g = h @ W (bf16 in, f32 math, bf16 out) ----------------
template <int DIN>
__launch_bounds__(256)
__global__ void kx_transform(const unsigned* __restrict__ h32,  // bf16 pairs, row stride DIN/2
                             const float* __restrict__ W,       // [DIN][128]
                             unsigned short* __restrict__ g,    // [n][128] bf16
                             int n_src) {
  constexpr int RS = DIN + 4;
  constexpr int HC = DIN / 2;
  __shared__ float rows[32 * RS];
  const int tid = threadIdx.x;
  const int nbase = blockIdx.x * 32;
  for (int idx = tid; idx < 32 * HC; idx += 256) {
    int r = idx / HC, cp = idx % HC;
    int n = nbase + r;
    unsigned u = (n < n_src) ? h32[(size_t)n * HC + cp] : 0u;
    rows[r * RS + cp * 2] = blo(u);
    rows[r * RS + cp * 2 + 1] = bhi(u);
  }
  __syncthreads();
  const int jg = tid % 32, ng = tid / 32;  // NG=8, NPT=4
  const int j0 = jg * 4;
  f4 acc[4];
#pragma unroll
  for (int p = 0; p < 4; ++p) acc[p] = (f4){0.f, 0.f, 0.f, 0.f};
#pragma unroll 2
  for (int k = 0; k < DIN; k += 4) {
    f4 w[4];
#pragma unroll
    for (int u = 0; u < 4; ++u) w[u] = *(const f4*)&W[(k + u) * 128 + j0];
#pragma unroll
    for (int p = 0; p < 4; ++p) {
      f4 r = *(const f4*)&rows[(ng + p * 8) * RS + k];
#pragma unroll
      for (int u = 0; u < 4; ++u) acc[p] += r[u] * w[u];
    }
  }
#pragma unroll
  for (int p = 0; p < 4; ++p) {
    const int n = nbase + ng + p * 8;
    if (n < n_src) {
      u16x4 o = {f2bf(acc[p][0]), f2bf(acc[p][1]), f2bf(acc[p][2]), f2bf(acc[p][3])};
      *(u16x4*)&g[(size_t)n * 128 + j0] = o;
    }
  }
}

// ---------------- sweep v2: slot-packed chunk-major gather for read-dst layers ----------------
// Wave = 4 slots x 16 lanes, owns one group of 4 read nodes. One dwordx4 gather fetches
// 4 different rows per instr; masked FMA into 4 per-node accumulators.
// Accumulators are 8 INDIVIDUALLY NAMED f4 registers (NOT arrays): f4[4] arrays were
// demoted by PromoteAlloca to LDS+scratch (r14 evidence: LDS_Block_Size=16384 with no
// __shared__, 5M bank conflicts, WRITE_SIZE 250MB vs 52MB logical).
template <bool FC>
__launch_bounds__(256, 4)
__global__ void k_sweep2(const unsigned* __restrict__ g32,  // [50K][64] u32 (2 bf16 each)
                         const int* __restrict__ rpg,       // [NGRP+1] group record starts
                         const unsigned* __restrict__ recs, // ((read&3)<<16)|intron
                         const float* __restrict__ rs_dst,
                         const float* __restrict__ bias,
                         const float* __restrict__ atts, int li,
                         unsigned* __restrict__ hout32,  // [N_READ][64] u32 rows
                         const float* __restrict__ fcw, const float* __restrict__ fcb,
                         float* __restrict__ fcout) {
  const int tid = threadIdx.x;
  const int wave = tid >> 6, lane = tid & 63;
  const int slot = lane >> 4, lc = lane & 15;
  const int group = blockIdx.x * 4 + wave;  // grid 12500 * 4 = 50000 = NGRP
  const int s = rpg[group], e = rpg[group + 1];

  // acc[node][cols lc*8..lc*8+7]: *A = first 4 cols, *B = last 4 cols
  f4 a0A = {0.f, 0.f, 0.f, 0.f}, a1A = a0A, a2A = a0A, a3A = a0A;
  f4 a0B = a0A, a1B = a0A, a2B = a0A, a3B = a0A;

  for (int base = s; base < e; base += 64) {
    int idx = base + lane;
    if (idx > N_EDGES - 1) idx = N_EDGES - 1;
    unsigned rec = recs[idx];  // one batch load per <=64 records
    int m = e - base;
    if (m > 64) m = 64;
    for (int r = 0; r < m; r += 4) {
      unsigned rc = (unsigned)__shfl((int)rec, r + slot, 64);
      int id = (int)(rc & 0xffffu);
      int nl = (int)((rc >> 16) & 3u);
      float act = ((r + slot) < m) ? 1.f : 0.f;
      u32x4 v = *(const u32x4*)(g32 + (size_t)id * 64 + lc * 4);  // 4 rows / instr
      f4 vA = {blo(v.x), bhi(v.x), blo(v.y), bhi(v.y)};
      f4 vB = {blo(v.z), bhi(v.z), blo(v.w), bhi(v.w)};
      float m0 = (nl == 0) ? act : 0.f;
      float m1 = (nl == 1) ? act : 0.f;
      float m2 = (nl == 2) ? act : 0.f;
      float m3 = (nl == 3) ? act : 0.f;
      a0A += vA * m0; a0B += vB * m0;
      a1A += vA * m1; a1B += vB * m1;
      a2A += vA * m2; a2B += vB * m2;
      a3A += vA * m3; a3B += vB * m3;
    }
  }

  // cross-slot reduce (each node's sum is spread over the 4 slots' lane sets)
  xred(a0A); xred(a0B);
  xred(a1A); xred(a1B);
  xred(a2A); xred(a2B);
  xred(a3A); xred(a3B);

  // slot s finishes node group*4+s
  f4 sA = a0A, sB = a0B;
  if (slot == 1) { sA = a1A; sB = a1B; }
  if (slot == 2) { sA = a2A; sB = a2B; }
  if (slot == 3) { sA = a3A; sB = a3B; }
  const int n = group * 4 + slot;
  const float rsd = rs_dst[n];
  const float gate = 1.f / (1.f + __expf(-atts[li]));
  f4 bA = *(const f4*)&bias[lc * 8];
  f4 bB = *(const f4*)&bias[lc * 8 + 4];
  f4 vA = (sA * rsd + bA) * gate;
  f4 vB = (sB * rsd + bB) * gate;
#pragma unroll
  for (int j = 0; j < 4; ++j) {
    vA[j] = fmaxf(vA[j], 0.f);
    vB[j] = fmaxf(vB[j], 0.f);
  }
  if constexpr (!FC) {
    vA *= rsd;  // prescale for next layer (rs_next == rs_dst here)
    vB *= rsd;
    u32x4 o;
    o.x = (unsigned)f2bf(vA[0]) | ((unsigned)f2bf(vA[1]) << 16);
    o.y = (unsigned)f2bf(vA[2]) | ((unsigned)f2bf(vA[3]) << 16);
    o.z = (unsigned)f2bf(vB[0]) | ((unsigned)f2bf(vB[1]) << 16);
    o.w = (unsigned)f2bf(vB[2]) | ((unsigned)f2bf(vB[3]) << 16);
    *(u32x4*)(hout32 + (size_t)n * 64 + lc * 4) = o;
  } else {
    // fc: lane lc holds cols lc*8..lc*8+7; fcw flat[k*2+c] = flat[lc*16 + 2j + c]
    f4 w0 = *(const f4*)&fcw[lc * 16];
    f4 w1 = *(const f4*)&fcw[lc * 16 + 4];
    f4 w2 = *(const f4*)&fcw[lc * 16 + 8];
    f4 w3 = *(const f4*)&fcw[lc * 16 + 12];
    float s0 = vA[0] * w0[0] + vA[1] * w0[2] + vA[2] * w1[0] + vA[3] * w1[2]
             + vB[0] * w2[0] + vB[1] * w2[2] + vB[2] * w3[0] + vB[3] * w3[2];
    float s1 = vA[0] * w0[1] + vA[1] * w0[3] + vA[2] * w1[1] + vA[3] * w1[3]
             + vB[0] * w2[1] + vB[1] * w2[3] + vB[2] * w3[1] + vB[3] * w3[3];
    s0 += __shfl_xor(s0, 1); s0 += __shfl_xor(s0, 2);
    s0 += __shfl_xor(s0, 4); s0 += __shfl_xor(s0, 8);
    s1 += __shfl_xor(s1, 1); s1 += __shfl_xor(s1, 2);
    s1 += __shfl_xor(s1, 4); s1 += __shfl_xor(s1, 8);
    if (lc == 0) {
      fcout[n * 2] = s0 + fcb[0];
      fcout[n * 2 + 1] = s1 + fcb[1];
    }
  }
}

// ---------------- fused aggregate + GEMM + epilogue layer (intron-dst: L0, L2, L4) ----------------
template <int DIN, int DOUT, bool BF16SRC, typename ET>
__launch_bounds__(256)
__global__ void k_layer(const void* __restrict__ hsrc_, const int* __restrict__ rp,
                        const ET* __restrict__ eidx, const float* __restrict__ rs_dst,
                        const float* __restrict__ W, const float* __restrict__ bias,
                        const float* __restrict__ atts, int li,
                        const float* __restrict__ rs_next,
                        void* __restrict__ hout_, int n_dst) {
  constexpr int NT = 32;
  constexpr int RSTR = DIN + 4;
  __shared__ float rows[NT * RSTR];
  __shared__ int rpl[NT + 1];
  const int tid = threadIdx.x;
  const int nbase = blockIdx.x * NT;
  const int team = tid >> 6, lane = tid & 63;
  const float* hs_f = (const float*)hsrc_;
  const unsigned short* hs_b = (const unsigned short*)hsrc_;

  constexpr int LPS = (DIN * (BF16SRC ? 2 : 4)) / 16;  // lanes per source row
  constexpr int SLOTS = 64 / LPS;
  const int slot = lane / LPS, lc = lane % LPS;

  if (tid <= NT) {
    int nn = nbase + tid;
    if (nn > n_dst) nn = n_dst;
    rpl[tid] = rp[nn];
  }
  __syncthreads();

  {
    int p0 = rpl[team * 8] + lane;
    if (p0 > N_EDGES - 1) p0 = N_EDGES - 1;
    int idsC = (int)eidx[p0];

    for (int t8 = 0; t8 < 8; ++t8) {
      const int t = team * 8 + t8;
      const int e0 = rpl[t], e1 = rpl[t + 1];
      const int deg = e1 - e0;
      int pn = e1 + lane;
      if (pn > N_EDGES - 1) pn = N_EDGES - 1;
      int idsN = (int)eidx[pn];

      f4 accA = {0.f, 0.f, 0.f, 0.f};
      f4 accB = {0.f, 0.f, 0.f, 0.f};
      int processed = 0;
      while (processed < deg) {
        int m = deg - processed;
        if (m > 64) m = 64;
        if (processed > 0) {
          int pr = e0 + processed + lane;
          if (pr > N_EDGES - 1) pr = N_EDGES - 1;
          idsC = (int)eidx[pr];
        }
        for (int r = 0; r < m; r += SLOTS) {
          int idv = __shfl(idsC, r + slot, 64);
          if constexpr (BF16SRC) {
            u32x4 v = *(const u32x4*)(hs_b + (size_t)idv * DIN + lc * 8);
            if (r + slot < m) {
              accA[0] += blo(v.x); accA[1] += bhi(v.x);
              accA[2] += blo(v.y); accA[3] += bhi(v.y);
              accB[0] += blo(v.z); accB[1] += bhi(v.z);
              accB[2] += blo(v.w); accB[3] += bhi(v.w);
            }
          } else {
            f4 v = *(const f4*)(hs_f + (size_t)idv * DIN + lc * 4);
            if (r + slot < m) accA += v;
          }
        }
        processed += m;
      }
      idsC = idsN;

#pragma unroll
      for (int off = LPS; off < 64; off <<= 1) {
#pragma unroll
        for (int k = 0; k < 4; ++k) accA[k] += __shfl_xor(accA[k], off);
        if constexpr (BF16SRC) {
#pragma unroll
          for (int k = 0; k < 4; ++k) accB[k] += __shfl_xor(accB[k], off);
        }
      }
      if (slot == 0) {
        const int n = nbase + t;
        const float rsd = (n < n_dst) ? rs_dst[n] : 0.f;
        if constexpr (BF16SRC) {
          *(f4*)&rows[t * RSTR + lc * 8] = accA * rsd;
          *(f4*)&rows[t * RSTR + lc * 8 + 4] = accB * rsd;
        } else {
          *(f4*)&rows[t * RSTR + lc * 4] = accA * rsd;
        }
      }
    }
  }
  __syncthreads();

  constexpr int JG = DOUT / 4;
  constexpr int NG = 256 / JG;
  constexpr int NPT = NT / NG;
  const int jg = tid % JG, ng = tid / JG;
  const int j0 = jg * 4;

  f4 acc[NPT];
#pragma unroll
  for (int p = 0; p < NPT; ++p) acc[p] = (f4){0.f, 0.f, 0.f, 0.f};

#pragma unroll 2
  for (int k = 0; k < DIN; k += 4) {
    f4 w[4];
#pragma unroll
    for (int u = 0; u < 4; ++u) w[u] = *(const f4*)&W[(k + u) * DOUT + j0];
#pragma unroll
    for (int p = 0; p < NPT; ++p) {
      f4 r = *(const f4*)&rows[(ng + p * NG) * RSTR + k];
#pragma unroll
      for (int u = 0; u < 4; ++u) acc[p] += r[u] * w[u];
    }
  }

  const float gate = 1.f / (1.f + __expf(-atts[li]));
  const f4 b4 = *(const f4*)&bias[j0];
#pragma unroll
  for (int p = 0; p < NPT; ++p) {
    const int nl = ng + p * NG;
    const int n = nbase + nl;
    if (n < n_dst) {
      f4 v = (acc[p] + b4) * gate;
#pragma unroll
      for (int c = 0; c < 4; ++c) v[c] = fmaxf(v[c], 0.f);
      if (rs_next) v *= rs_next[n];
      u16x4 o = {f2bf(v[0]), f2bf(v[1]), f2bf(v[2]), f2bf(v[3])};
      *(u16x4*)&((unsigned short*)hout_)[(size_t)n * DOUT + j0] = o;
    }
  }
}

extern "C" void kernel_launch(void* const* d_in, const int* in_sizes, int n_in,
                              void* d_out, int out_size, void* d_ws, size_t ws_size,
                              hipStream_t stream) {
  const float* h_read = (const float*)d_in[0];
  const int* esrc = (const int*)d_in[1];
  const int* edst = (const int*)d_in[2];
  const float* W0 = (const float*)d_in[3];
  const float* b0 = (const float*)d_in[4];
  const float* W1 = (const float*)d_in[5];
  const float* b1 = (const float*)d_in[6];
  const float* W2 = (const float*)d_in[7];
  const float* b2 = (const float*)d_in[8];
  const float* W3 = (const float*)d_in[9];
  const float* b3 = (const float*)d_in[10];
  const float* W4 = (const float*)d_in[11];
  const float* b4 = (const float*)d_in[12];
  const float* W5 = (const float*)d_in[13];
  const float* b5 = (const float*)d_in[14];
  const float* atts = (const float*)d_in[15];
  const float* fcw = (const float*)d_in[16];
  const float* fcb = (const float*)d_in[17];
  float* out = (float*)d_out;

  char* w = (char*)d_ws;
  size_t off = 0;
  auto alloc = [&](size_t bytes) -> void* {
    void* p = w + off;
    off += (bytes + 15) & ~(size_t)15;
    return p;
  };
  int* rp_i = (int*)alloc((N_INTRON + 1) * 4);
  int* rpg = (int*)alloc((NGRP + 1) * 4);  // per-group record starts
  int* bsum = (int*)alloc(1024 * 4);
  float* rs_r = (float*)alloc(N_READ * 4);
  float* rs_i = (float*)alloc(N_INTRON * 4);
  unsigned* recs = (unsigned*)alloc((size_t)N_EDGES * 4);  // sweep records
  int* csr_si_i = (int*)alloc(N_EDGES * 4);                // read ids by intron
  float* W0p = (float*)alloc(16 * 64 * 4);
  int* histI = (int*)alloc(NITEMS * 4);
  int* scanI = (int*)alloc((NITEMS + 1) * 4);
  int* histR = (int*)alloc(NITEMS * 4);
  int* scanR = (int*)alloc((NITEMS + 1) * 4);
  unsigned short* hR = (unsigned short*)alloc((size_t)N_READ * 128 * 2);    // bf16 features
  unsigned short* hI = (unsigned short*)alloc((size_t)N_INTRON * 128 * 2);  // bf16 features
  unsigned short* g = (unsigned short*)alloc((size_t)N_INTRON * 128 * 2);   // pre-transformed
  // Time-multiplexed aliases inside hR's 51.2 MB (dead until the L1 sweep writes it):
  //   h16 (f32, 12.8 MB) lives prep_h0 -> L0 at hR+0;
  //   bucketed edge records live kb_scatter -> kb_fine at hR+16MB (2x8 MB).
  float* h16 = (float*)hR;
  unsigned* bI = (unsigned*)((char*)hR + (size_t)16 * 1024 * 1024);
  unsigned* bR = bI + N_EDGES;

  // --- CSR build ---
  kb_hist<<<NB, 256, 0, stream>>>(esrc, edst, histI, histR);
  k_scan1<<<NITEMS / 256, 256, 0, stream>>>(histI, scanI, bsum, NITEMS);
  k_scan2<<<1, 1024, 0, stream>>>(bsum, NITEMS / 256);
  k_scan3b<<<NITEMS / 256, 256, 0, stream>>>(scanI, bsum, NITEMS);
  k_scan1<<<NITEMS / 256, 256, 0, stream>>>(histR, scanR, bsum, NITEMS);
  k_scan2<<<1, 1024, 0, stream>>>(bsum, NITEMS / 256);
  k_scan3b<<<NITEMS / 256, 256, 0, stream>>>(scanR, bsum, NITEMS);
  kb_scatter<<<NB, 256, 0, stream>>>(esrc, edst, scanI, scanR, bI, bR);
  kb_fine<64, SH_I, int><<<NBUK, 256, 0, stream>>>(bI, scanI, rp_i, rs_i, csr_si_i, N_INTRON);
  kb_fine_r<<<NBUK, 256, 0, stream>>>(bR, scanR, rpg, rs_r, recs, N_READ);

  k_prep_h0<<<(N_READ * 16 + 255) / 256, 256, 0, stream>>>(h_read, rs_r, h16);
  k_prep_W0<<<4, 256, 0, stream>>>(W0, W0p);

  const int gI = (N_INTRON + 31) / 32;  // 1563
  const int gT = (N_INTRON + 31) / 32;  // transform grid
  const int gS = NGRP / 4;              // 12500 sweep blocks (4 groups each)

  // L0: read->intron, 16(pad)->64, f32 src, write hI bf16 (prescaled rs_i)
  k_layer<16, 64, false, int><<<gI, 256, 0, stream>>>(
      h16, rp_i, csr_si_i, rs_i, W0p, b0, atts, 0, rs_i, hI, N_INTRON);
  // L1: transform hI(64) @ W1 -> g(128), then slot-packed sweep -> hR (prescaled rs_r)
  kx_transform<64><<<gT, 256, 0, stream>>>((const unsigned*)hI, W1, g, N_INTRON);
  k_sweep2<false><<<gS, 256, 0, stream>>>((const unsigned*)g, rpg, recs, rs_r, b1, atts, 1,
                                          (unsigned*)hR, nullptr, nullptr, nullptr);
  // L2: read->intron, 128->128, bf16 src hR, write hI (prescaled rs_i)
  k_layer<128, 128, true, int><<<gI, 256, 0, stream>>>(
      hR, rp_i, csr_si_i, rs_i, W2, b2, atts, 2, rs_i, hI, N_INTRON);
  // L3: transform hI @ W3 -> g, sweep -> hR
  kx_transform<128><<<gT, 256, 0, stream>>>((const unsigned*)hI, W3, g, N_INTRON);
  k_sweep2<false><<<gS, 256, 0, stream>>>((const unsigned*)g, rpg, recs, rs_r, b3, atts, 3,
                                          (unsigned*)hR, nullptr, nullptr, nullptr);
  // L4: read->intron, bf16 src hR, write hI
  k_layer<128, 128, true, int><<<gI, 256, 0, stream>>>(
      hR, rp_i, csr_si_i, rs_i, W4, b4, atts, 4, rs_i, hI, N_INTRON);
  // L5: transform hI @ W5 -> g, sweep with fused fc -> out
  kx_transform<128><<<gT, 256, 0, stream>>>((const unsigned*)hI, W5, g, N_INTRON);
  k_sweep2<true><<<gS, 256, 0, stream>>>((const unsigned*)g, rpg, recs, rs_r, b5, atts, 5,
                                         nullptr, fcw, fcb, out);
}